// Round 4
// baseline (168.571 us; speedup 1.0000x reference)
//
#include <hip/hip_runtime.h>
#include <cstdint>
#include <cstddef>

#define BB 8
#define CC 256
#define HH 100
#define WW 100
#define HW 10000
#define KTOP 1500

// ---- ws layout (float offsets) ----
#define WS_AVG   0        // 2048
#define WS_MAX   2048     // 2048
#define WS_GAP   4096     // 2048
#define WS_CA    6144     // 2048
#define WS_CASW  8192     // 2048
#define WS_SW    10240    // 80000
#define WS_SAVG  90240    // 80000
#define WS_SMAX  170240   // 80000
#define WS_SEL   250240   // 8 ints
#define WS_AK    250248   // u64[8*1500] (byte off %8==0)

// ---- out layout (float offsets) ----
#define O_BND 0
#define O_RAW 24
#define O_CNT 48
#define O_NQ  56
#define O_WMAP 64
#define O_REF 80064

__device__ __forceinline__ float clip5(float v){ return fminf(fmaxf(v, -5.f), 5.f); }
__device__ __forceinline__ float softplusf(float x){ return fmaxf(x, 0.f) + log1pf(expf(-fabsf(x))); }
__device__ __forceinline__ float sigmoidf(float x){ return 1.f / (1.f + expf(-x)); }

__device__ __forceinline__ float wsum(float v){
#pragma unroll
  for (int o = 32; o; o >>= 1) v += __shfl_down(v, o, 64);
  return v;
}
__device__ __forceinline__ float wmaxr(float v){
#pragma unroll
  for (int o = 32; o; o >>= 1) v = fmaxf(v, __shfl_down(v, o, 64));
  return v;
}

// block=256 (4 waves) sum, broadcast to all threads
__device__ __forceinline__ float bsum256(float v, volatile float* red){
  v = wsum(v);
  int w = threadIdx.x >> 6;
  if ((threadIdx.x & 63) == 0) red[w] = v;
  __syncthreads();
  float r = (red[0] + red[1]) + (red[2] + red[3]);
  __syncthreads();
  return r;
}

// ---------------- kernel 1: per-(b,c) HW reductions over df (avg+max) and ef (avg) ----------------
// 2500 float4 per row: 9 full sweeps of 256 threads + 196-thread tail, all preloaded for ILP.
__global__ __launch_bounds__(256) void k_reduce(const float* __restrict__ df,
                                                const float* __restrict__ ef,
                                                float* __restrict__ ws){
  int blk = blockIdx.x;
  bool isDf = blk < 2048;
  int bc = isDf ? blk : blk - 2048;
  const float4* __restrict__ src =
      reinterpret_cast<const float4*>((isDf ? df : ef) + (size_t)bc * HW);
  int t = threadIdx.x;
  bool tail = t < (2500 - 9 * 256);    // 196
  float4 v[9];
#pragma unroll
  for (int k = 0; k < 9; k++) v[k] = src[t + 256 * k];
  float4 v9 = src[tail ? (2304 + t) : t];   // dummy L1-hit re-read when !tail

  float s = 0.f, m = -1e30f;
#pragma unroll
  for (int k = 0; k < 9; k++){
    float a = clip5(v[k].x), b = clip5(v[k].y), c = clip5(v[k].z), d = clip5(v[k].w);
    s += (a + b) + (c + d);
    m = fmaxf(m, fmaxf(fmaxf(a, b), fmaxf(c, d)));
  }
  if (tail){
    float a = clip5(v9.x), b = clip5(v9.y), c = clip5(v9.z), d = clip5(v9.w);
    s += (a + b) + (c + d);
    m = fmaxf(m, fmaxf(fmaxf(a, b), fmaxf(c, d)));
  }

  __shared__ float rs[4], rm[4];
  s = wsum(s); m = wmaxr(m);
  int w = t >> 6;
  if ((t & 63) == 0){ rs[w] = s; rm[w] = m; }
  __syncthreads();
  if (t == 0){
    float S = (rs[0] + rs[1]) + (rs[2] + rs[3]);
    float M = fmaxf(fmaxf(rm[0], rm[1]), fmaxf(rm[2], rm[3]));
    if (isDf){ ws[WS_AVG + bc] = S * (1.f / HW); ws[WS_MAX + bc] = M; }
    else      { ws[WS_GAP + bc] = S * (1.f / HW); }
  }
}

// ---------------- kernel 2: per-batch heads (boundary MLP, count regressor, channel attn) --------
__global__ __launch_bounds__(256) void k_head(float* __restrict__ ws,
    const float* __restrict__ ln_g, const float* __restrict__ ln_b,
    const float* __restrict__ fw1, const float* __restrict__ fb1,
    const float* __restrict__ fw2, const float* __restrict__ fb2,
    const float* __restrict__ crg, const float* __restrict__ crb,
    const float* __restrict__ cw1, const float* __restrict__ cb1,
    const float* __restrict__ cw2, const float* __restrict__ cb2,
    const float* __restrict__ caw1, const float* __restrict__ cab1,
    const float* __restrict__ caw2, const float* __restrict__ cab2,
    const float* __restrict__ sw_w, float* __restrict__ out){
  int b = blockIdx.x, t = threadIdx.x;
  __shared__ float red[4];
  __shared__ __align__(16) float gl[512];
  __shared__ __align__(16) float hl[256];
  __shared__ float rawl[3];
  __shared__ float bnd[3];
  __shared__ __align__(16) float al[16];

  float fa = ws[WS_AVG + b * CC + t];
  float fm = ws[WS_MAX + b * CC + t];

  // LayerNorm over 512 (concat avg,max)
  float s  = bsum256(fa + fm, red);
  float s2 = bsum256(fa * fa + fm * fm, red);
  float mean = s * (1.f / 512.f);
  float var  = s2 * (1.f / 512.f) - mean * mean;
  float inv  = rsqrtf(var + 1e-5f);
  gl[t]       = (fa - mean) * inv * ln_g[t]       + ln_b[t];
  gl[t + 256] = (fm - mean) * inv * ln_g[t + 256] + ln_b[t + 256];
  __syncthreads();

  // fc_boundary layer1: 512->256, relu (float4 dot)
  {
    const float4* __restrict__ glv = reinterpret_cast<const float4*>(gl);
    const float4* __restrict__ w1v = reinterpret_cast<const float4*>(fw1 + t * 512);
    float acc = fb1[t];
#pragma unroll 8
    for (int k = 0; k < 128; k++){
      float4 g = glv[k], w = w1v[k];
      acc += g.x * w.x + g.y * w.y + g.z * w.z + g.w * w.w;
    }
    hl[t] = fmaxf(acc, 0.f);
  }
  __syncthreads();
  // layer2: 256->3
  if (t < 3){
    const float4* __restrict__ hv  = reinterpret_cast<const float4*>(hl);
    const float4* __restrict__ w2v = reinterpret_cast<const float4*>(fw2 + t * 256);
    float r = fb2[t];
#pragma unroll 8
    for (int k = 0; k < 64; k++){
      float4 h = hv[k], w = w2v[k];
      r += h.x * w.x + h.y * w.y + h.z * w.z + h.w * w.w;
    }
    rawl[t] = r;
  }
  __syncthreads();
  if (t == 0){
    float cum = 0.f;
    for (int o = 0; o < 3; o++){
      float rv = rawl[o];
      out[O_RAW + b * 3 + o] = rv;
      cum += softplusf(rv) * 150.f + 5.f;  // SCALE=150
      out[O_BND + b * 3 + o] = cum;
      bnd[o] = cum;
    }
  }
  __syncthreads();

  // count regressor: LN(256) -> 256 relu -> 1 softplus
  float sc  = bsum256(fa, red);
  float sc2 = bsum256(fa * fa, red);
  float m2 = sc * (1.f / 256.f);
  float v2 = sc2 * (1.f / 256.f) - m2 * m2;
  float inv2 = rsqrtf(v2 + 1e-5f);
  hl[t] = (fa - m2) * inv2 * crg[t] + crb[t];
  __syncthreads();
  float h2;
  {
    const float4* __restrict__ hv  = reinterpret_cast<const float4*>(hl);
    const float4* __restrict__ w1v = reinterpret_cast<const float4*>(cw1 + t * 256);
    float acc2 = cb1[t];
#pragma unroll 8
    for (int k = 0; k < 64; k++){
      float4 h = hv[k], w = w1v[k];
      acc2 += h.x * w.x + h.y * w.y + h.z * w.z + h.w * w.w;
    }
    h2 = fmaxf(acc2, 0.f);
  }
  float pv = bsum256(h2 * cw2[t], red);
  if (t == 0){
    float pred = softplusf(pv + cb2[0]);
    out[O_CNT + b] = pred;
    int lvl = (pred > bnd[0]) + (pred > bnd[1]) + (pred > bnd[2]);
    const float QL[4] = {300.f, 500.f, 900.f, 1500.f};
    out[O_NQ + b] = QL[lvl];
  }

  // channel attention: gap -> 16 relu -> 256 sigmoid
  float gp = ws[WS_GAP + b * CC + t];
  __syncthreads();
  hl[t] = gp;
  __syncthreads();
  if (t < 16){
    const float4* __restrict__ hv  = reinterpret_cast<const float4*>(hl);
    const float4* __restrict__ w1v = reinterpret_cast<const float4*>(caw1 + t * 256);
    float a = cab1[t];
#pragma unroll 8
    for (int k = 0; k < 64; k++){
      float4 h = hv[k], w = w1v[k];
      a += h.x * w.x + h.y * w.y + h.z * w.z + h.w * w.w;
    }
    al[t] = fmaxf(a, 0.f);
  }
  __syncthreads();
  float a2 = cab2[t];
  {
    const float4* __restrict__ av  = reinterpret_cast<const float4*>(al);
    const float4* __restrict__ w2v = reinterpret_cast<const float4*>(caw2 + t * 16);
#pragma unroll
    for (int k = 0; k < 4; k++){
      float4 h = av[k], w = w2v[k];
      a2 += h.x * w.x + h.y * w.y + h.z * w.z + h.w * w.w;
    }
  }
  float cav = sigmoidf(a2);
  ws[WS_CA + b * CC + t]   = cav;
  ws[WS_CASW + b * CC + t] = cav * sw_w[t];
}

// ---------------- kernel 3: second ef pass — per-pixel channel reductions (float4 pixels) -------
__global__ __launch_bounds__(128) void k_pixel(const float* __restrict__ ef,
                                               float* __restrict__ ws){
  int b = blockIdx.y;
  int q = blockIdx.x * 128 + threadIdx.x;   // quad index (4 pixels), 0..2499
  __shared__ float caL[256], cswL[256];
  caL[threadIdx.x]        = ws[WS_CA + b * CC + threadIdx.x];
  caL[threadIdx.x + 128]  = ws[WS_CA + b * CC + threadIdx.x + 128];
  cswL[threadIdx.x]       = ws[WS_CASW + b * CC + threadIdx.x];
  cswL[threadIdx.x + 128] = ws[WS_CASW + b * CC + threadIdx.x + 128];
  __syncthreads();
  if (q >= HW / 4) return;
  const float4* __restrict__ base =
      reinterpret_cast<const float4*>(ef + (size_t)b * CC * HW) + q;
  float4 sum = {0.f, 0.f, 0.f, 0.f};
  float4 mx  = {-1e30f, -1e30f, -1e30f, -1e30f};
  float4 sw  = {0.f, 0.f, 0.f, 0.f};
#pragma unroll 8
  for (int c = 0; c < CC; c++){
    float4 v = base[(size_t)c * (HW / 4)];
    float ca = caL[c], cs = cswL[c];
    float a = clip5(v.x), bb2 = clip5(v.y), cc2 = clip5(v.z), dd = clip5(v.w);
    sum.x += a * ca;  sum.y += bb2 * ca;  sum.z += cc2 * ca;  sum.w += dd * ca;
    mx.x = fmaxf(mx.x, a * ca);  mx.y = fmaxf(mx.y, bb2 * ca);
    mx.z = fmaxf(mx.z, cc2 * ca); mx.w = fmaxf(mx.w, dd * ca);
    sw.x = fmaf(a, cs, sw.x);  sw.y = fmaf(bb2, cs, sw.y);
    sw.z = fmaf(cc2, cs, sw.z); sw.w = fmaf(dd, cs, sw.w);
  }
  float4 avg = {sum.x * (1.f / 256.f), sum.y * (1.f / 256.f),
                sum.z * (1.f / 256.f), sum.w * (1.f / 256.f)};
  reinterpret_cast<float4*>(ws + WS_SAVG + (size_t)b * HW)[q] = avg;
  reinterpret_cast<float4*>(ws + WS_SMAX + (size_t)b * HW)[q] = mx;
  reinterpret_cast<float4*>(ws + WS_SW   + (size_t)b * HW)[q] = sw;
}

// ---------------- kernel 4: 7x7 spatial-attn conv + wmap ----------------
__global__ __launch_bounds__(256) void k_conv(const float* __restrict__ ws,
                                              const float* __restrict__ sa_w,
                                              const float* __restrict__ sw_b,
                                              float* __restrict__ out){
  __shared__ float wc[98];
  if (threadIdx.x < 98) wc[threadIdx.x] = sa_w[threadIdx.x];
  __syncthreads();
  int b = blockIdx.y;
  int p = blockIdx.x * 256 + threadIdx.x;
  if (p >= HW) return;
  int h = p / WW, w = p - h * WW;
  const float* s0 = ws + WS_SAVG + (size_t)b * HW;
  const float* s1 = ws + WS_SMAX + (size_t)b * HW;
  float acc = 0.f;
#pragma unroll
  for (int kh = 0; kh < 7; kh++){
    int hy = h + kh - 3;
    if (hy < 0 || hy >= HH) continue;
#pragma unroll
    for (int kw = 0; kw < 7; kw++){
      int wx = w + kw - 3;
      if (wx < 0 || wx >= WW) continue;
      int q = hy * WW + wx;
      acc += s0[q] * wc[kh * 7 + kw] + s1[q] * wc[49 + kh * 7 + kw];
    }
  }
  float wm = sigmoidf(ws[WS_SW + (size_t)b * HW + p] * sigmoidf(acc) + sw_b[0]);
  out[O_WMAP + (size_t)b * HW + p] = wm;
}

// ---------------- kernel 5: per-batch threshold find (4-way search) + compact + ties ----------
// All wmap values are positive floats -> uint bit-pattern compare == float compare.
// Register tile rv[j] holds global index j*1024 + t, so chunked scans need no LDS mirror.
__global__ __launch_bounds__(1024) void k_select(const float* __restrict__ outw,
                                                 float* __restrict__ ws,
                                                 float* __restrict__ out){
  __shared__ unsigned long long red64[16];
  __shared__ unsigned red32[16];
  __shared__ unsigned slo, shi, sbc;
  __shared__ unsigned acnt, runbase;
  int b = blockIdx.x, t = threadIdx.x;
  int w = t >> 6, lane = t & 63;

  const float* src = outw + O_WMAP + (size_t)b * HW;
  unsigned rv[10];
#pragma unroll
  for (int j = 0; j < 10; j++){
    int i = t + j * 1024;
    rv[j] = (i < HW) ? __float_as_uint(src[i]) : 0u;  // 0 sentinel never counted (> u fails)
  }

  // find vthr = min u such that count(v > u) < KTOP, resolving 2 bits/round via 3 quartile
  // probes whose block counts are packed into one u64 (16-bit fields; total <= 10000).
  unsigned lo = 0u, hi = 0xFFFFFFFFu;
  while (lo < hi){
    unsigned span = hi - lo;
    unsigned q1 = lo + (span >> 2);
    unsigned q2 = lo + (span >> 1);
    unsigned q3 = lo + span - (span >> 2);
    unsigned long long pk = 0;
#pragma unroll
    for (int j = 0; j < 10; j++){
      unsigned v = rv[j];
      pk += (unsigned long long)(v > q1)
          + ((unsigned long long)(v > q2) << 16)
          + ((unsigned long long)(v > q3) << 32);
    }
#pragma unroll
    for (int o = 32; o; o >>= 1) pk += __shfl_down(pk, o, 64);
    if (lane == 0) red64[w] = pk;
    __syncthreads();
    if (t == 0){
      unsigned long long tot = 0;
#pragma unroll
      for (int q = 0; q < 16; q++) tot += red64[q];
      unsigned c1 = (unsigned)(tot & 0xFFFFu);
      unsigned c2 = (unsigned)((tot >> 16) & 0xFFFFu);
      unsigned c3 = (unsigned)((tot >> 32) & 0xFFFFu);
      unsigned nlo, nhi;
      if (c1 < (unsigned)KTOP)      { nlo = lo;      nhi = q1; }
      else if (c2 < (unsigned)KTOP) { nlo = q1 + 1u; nhi = q2; }
      else if (c3 < (unsigned)KTOP) { nlo = q2 + 1u; nhi = q3; }
      else                          { nlo = q3 + 1u; nhi = hi; }
      slo = nlo; shi = nhi;
    }
    __syncthreads();
    lo = slo; hi = shi;
    __syncthreads();
  }
  unsigned vthr = lo;

  // count strictly greater (nabove)
  {
    unsigned c = 0;
#pragma unroll
    for (int j = 0; j < 10; j++) c += (rv[j] > vthr) ? 1u : 0u;
#pragma unroll
    for (int o = 32; o; o >>= 1) c += __shfl_down((int)c, o, 64);
    if (lane == 0) red32[w] = c;
    __syncthreads();
    if (t == 0){
      unsigned tot = 0;
#pragma unroll
      for (int q = 0; q < 16; q++) tot += red32[q];
      sbc = tot;
      acnt = 0; runbase = 0;
    }
    __syncthreads();
  }
  unsigned nabove = sbc;                 // < KTOP by construction
  int neq = KTOP - (int)nabove;          // >= 1; #(v==vthr) >= neq guaranteed
  if (t == 0) reinterpret_cast<int*>(ws)[WS_SEL + b] = (int)nabove;

  // compact strictly-greater candidates to ws (wave-aggregated atomics; order-agnostic)
  unsigned long long* AK = reinterpret_cast<unsigned long long*>(ws + WS_AK) + (size_t)b * KTOP;
#pragma unroll
  for (int j = 0; j < 10; j++){
    int i = t + j * 1024;
    bool p = (i < HW) && (rv[j] > vthr);
    unsigned long long m = __ballot(p);
    unsigned base = 0;
    if (lane == 0 && m) base = atomicAdd(&acnt, (unsigned)__popcll(m));
    base = (unsigned)__shfl((int)base, 0, 64);
    if (p){
      unsigned pos = base + (unsigned)__popcll(m & ((1ull << lane) - 1ull));
      AK[pos] = ((unsigned long long)rv[j] << 32) | (unsigned long long)(0xFFFFFFFFu - (unsigned)i);
    }
  }

  // ties (== vthr): first `neq` by ascending index, ordered block scan with early exit
  for (int j = 0; j < 10; j++){
    int i = j * 1024 + t;
    bool eq = (i < HW) && (rv[j] == vthr);
    unsigned long long bal = __ballot(eq);
    if (lane == 0) red32[w] = (unsigned)__popcll(bal);
    __syncthreads();
    unsigned pre = runbase;
    for (int q = 0; q < w; q++) pre += red32[q];
    unsigned myr = pre + (unsigned)__popcll(bal & ((1ull << lane) - 1ull));
    if (eq && myr < (unsigned)neq){
      int pos = (int)nabove + (int)myr;
      float y = ((float)(i / WW) + 0.5f) * (1.f / HH);
      float x = ((float)(i % WW) + 0.5f) * (1.f / WW);
      float* rp = out + O_REF + ((size_t)b * KTOP + pos) * 4;
      rp[0] = x; rp[1] = y; rp[2] = 0.05f; rp[3] = 0.05f;
    }
    __syncthreads();
    if (t == 0){
      unsigned tot = 0;
#pragma unroll
      for (int q = 0; q < 16; q++) tot += red32[q];
      runbase += tot;
    }
    __syncthreads();
    if (runbase >= (unsigned)neq) break;   // uniform
  }
}

// ---------------- kernel 6: exact rank of strictly-greater candidates (96 blocks) -----------
__global__ __launch_bounds__(128) void k_rank(const float* __restrict__ ws,
                                              float* __restrict__ out){
  int b = blockIdx.x, chunk = blockIdx.y, t = threadIdx.x;
  int nA = reinterpret_cast<const int*>(ws)[WS_SEL + b];
  __shared__ unsigned long long K[KTOP];
  const unsigned long long* AK =
      reinterpret_cast<const unsigned long long*>(ws + WS_AK) + (size_t)b * KTOP;
  for (int i = t; i < nA; i += 128) K[i] = AK[i];
  __syncthreads();
  int i = chunk * 128 + t;
  if (i >= nA) return;
  unsigned long long Ki = K[i];
  int r = 0;
  for (int j = 0; j < nA; j++) r += (K[j] > Ki);
  unsigned idx = 0xFFFFFFFFu - (unsigned)(Ki & 0xFFFFFFFFull);
  float y = ((float)(idx / WW) + 0.5f) * (1.f / HH);
  float x = ((float)(idx % WW) + 0.5f) * (1.f / WW);
  float* rp = out + O_REF + ((size_t)b * KTOP + r) * 4;
  rp[0] = x; rp[1] = y; rp[2] = 0.05f; rp[3] = 0.05f;
}

extern "C" void kernel_launch(void* const* d_in, const int* in_sizes, int n_in,
                              void* d_out, int out_size, void* d_ws, size_t ws_size,
                              hipStream_t stream) {
  const float* df   = (const float*)d_in[0];
  const float* ef   = (const float*)d_in[1];
  const float* ln_g = (const float*)d_in[2];
  const float* ln_b = (const float*)d_in[3];
  const float* fw1  = (const float*)d_in[4];
  const float* fb1  = (const float*)d_in[5];
  const float* fw2  = (const float*)d_in[6];
  const float* fb2  = (const float*)d_in[7];
  const float* crg  = (const float*)d_in[8];
  const float* crb  = (const float*)d_in[9];
  const float* cw1  = (const float*)d_in[10];
  const float* cb1  = (const float*)d_in[11];
  const float* cw2  = (const float*)d_in[12];
  const float* cb2  = (const float*)d_in[13];
  const float* caw1 = (const float*)d_in[14];
  const float* cab1 = (const float*)d_in[15];
  const float* caw2 = (const float*)d_in[16];
  const float* cab2 = (const float*)d_in[17];
  const float* sa_w = (const float*)d_in[18];
  const float* sw_w = (const float*)d_in[19];
  const float* sw_b = (const float*)d_in[20];
  float* out = (float*)d_out;
  float* ws  = (float*)d_ws;

  k_reduce<<<4096, 256, 0, stream>>>(df, ef, ws);
  k_head<<<8, 256, 0, stream>>>(ws, ln_g, ln_b, fw1, fb1, fw2, fb2,
                                crg, crb, cw1, cb1, cw2, cb2,
                                caw1, cab1, caw2, cab2, sw_w, out);
  k_pixel<<<dim3(20, 8), 128, 0, stream>>>(ef, ws);
  k_conv<<<dim3(40, 8), 256, 0, stream>>>(ws, sa_w, sw_b, out);
  k_select<<<8, 1024, 0, stream>>>(out, ws, out);
  k_rank<<<dim3(8, 12), 128, 0, stream>>>(ws, out);
}

// Round 5
// 146.663 us; speedup vs baseline: 1.1494x; 1.1494x over previous
//
#include <hip/hip_runtime.h>
#include <cstdint>
#include <cstddef>

#define BB 8
#define CC 256
#define HH 100
#define WW 100
#define HW 10000
#define KTOP 1500
#define QB 64

// ---- ws layout (float offsets) ----
#define WS_AVG   0        // 2048
#define WS_MAX   2048     // 2048
#define WS_GAP   4096     // 2048
#define WS_CA    6144     // 2048
#define WS_CASW  8192     // 2048
#define WS_SW    10240    // 80000
#define WS_SAVG  90240    // 80000
#define WS_SMAX  170240   // 80000
#define WS_SEL   250240   // 8 ints
#define WS_AK    250248   // u64[8*1500] (byte off %8==0)

// ---- out layout (float offsets) ----
#define O_BND 0
#define O_RAW 24
#define O_CNT 48
#define O_NQ  56
#define O_WMAP 64
#define O_REF 80064

__device__ __forceinline__ float clip5(float v){ return fminf(fmaxf(v, -5.f), 5.f); }
__device__ __forceinline__ float softplusf(float x){ return fmaxf(x, 0.f) + log1pf(expf(-fabsf(x))); }
__device__ __forceinline__ float sigmoidf(float x){ return 1.f / (1.f + expf(-x)); }

__device__ __forceinline__ float wsum(float v){
#pragma unroll
  for (int o = 32; o; o >>= 1) v += __shfl_down(v, o, 64);
  return v;
}
__device__ __forceinline__ float wmaxr(float v){
#pragma unroll
  for (int o = 32; o; o >>= 1) v = fmaxf(v, __shfl_down(v, o, 64));
  return v;
}

// block=256 (4 waves) sum, broadcast to all threads
__device__ __forceinline__ float bsum256(float v, volatile float* red){
  v = wsum(v);
  int w = threadIdx.x >> 6;
  if ((threadIdx.x & 63) == 0) red[w] = v;
  __syncthreads();
  float r = (red[0] + red[1]) + (red[2] + red[3]);
  __syncthreads();
  return r;
}

// ---------------- kernel 1: per-(b,c) HW reductions over df (avg+max) and ef (avg) ----------------
// 10-deep float4 preload pinned by sched_barrier so the compiler cannot collapse the ILP.
__global__ __launch_bounds__(256) void k_reduce(const float* __restrict__ df,
                                                const float* __restrict__ ef,
                                                float* __restrict__ ws){
  int blk = blockIdx.x;
  bool isDf = blk < 2048;
  int bc = isDf ? blk : blk - 2048;
  const float4* __restrict__ src =
      reinterpret_cast<const float4*>((isDf ? df : ef) + (size_t)bc * HW);
  int t = threadIdx.x;
  float4 v[10];
#pragma unroll
  for (int k = 0; k < 10; k++){
    int idx = t + 256 * k;
    v[k] = src[idx < 2500 ? idx : (idx - 2500)];   // wrap tail -> L1 re-hit
  }
  __builtin_amdgcn_sched_barrier(0);   // keep all 10 loads in flight

  float s = 0.f, m = -1e30f;
#pragma unroll
  for (int k = 0; k < 9; k++){
    float a = clip5(v[k].x), b = clip5(v[k].y), c = clip5(v[k].z), d = clip5(v[k].w);
    s += (a + b) + (c + d);
    m = fmaxf(m, fmaxf(fmaxf(a, b), fmaxf(c, d)));
  }
  if (t < (2500 - 9 * 256)){           // 196-thread tail
    float a = clip5(v[9].x), b = clip5(v[9].y), c = clip5(v[9].z), d = clip5(v[9].w);
    s += (a + b) + (c + d);
    m = fmaxf(m, fmaxf(fmaxf(a, b), fmaxf(c, d)));
  }

  __shared__ float rs[4], rm[4];
  s = wsum(s); m = wmaxr(m);
  int w = t >> 6;
  if ((t & 63) == 0){ rs[w] = s; rm[w] = m; }
  __syncthreads();
  if (t == 0){
    float S = (rs[0] + rs[1]) + (rs[2] + rs[3]);
    float M = fmaxf(fmaxf(rm[0], rm[1]), fmaxf(rm[2], rm[3]));
    if (isDf){ ws[WS_AVG + bc] = S * (1.f / HW); ws[WS_MAX + bc] = M; }
    else      { ws[WS_GAP + bc] = S * (1.f / HW); }
  }
}

// ---------------- kernel 2: per-batch heads (boundary MLP, count regressor, channel attn) --------
__global__ __launch_bounds__(256) void k_head(float* __restrict__ ws,
    const float* __restrict__ ln_g, const float* __restrict__ ln_b,
    const float* __restrict__ fw1, const float* __restrict__ fb1,
    const float* __restrict__ fw2, const float* __restrict__ fb2,
    const float* __restrict__ crg, const float* __restrict__ crb,
    const float* __restrict__ cw1, const float* __restrict__ cb1,
    const float* __restrict__ cw2, const float* __restrict__ cb2,
    const float* __restrict__ caw1, const float* __restrict__ cab1,
    const float* __restrict__ caw2, const float* __restrict__ cab2,
    const float* __restrict__ sw_w, float* __restrict__ out){
  int b = blockIdx.x, t = threadIdx.x;
  __shared__ float red[4];
  __shared__ __align__(16) float gl[512];
  __shared__ __align__(16) float hl[256];
  __shared__ float rawl[3];
  __shared__ float bnd[3];
  __shared__ __align__(16) float al[16];

  float fa = ws[WS_AVG + b * CC + t];
  float fm = ws[WS_MAX + b * CC + t];

  // LayerNorm over 512 (concat avg,max)
  float s  = bsum256(fa + fm, red);
  float s2 = bsum256(fa * fa + fm * fm, red);
  float mean = s * (1.f / 512.f);
  float var  = s2 * (1.f / 512.f) - mean * mean;
  float inv  = rsqrtf(var + 1e-5f);
  gl[t]       = (fa - mean) * inv * ln_g[t]       + ln_b[t];
  gl[t + 256] = (fm - mean) * inv * ln_g[t + 256] + ln_b[t + 256];
  __syncthreads();

  // fc_boundary layer1: 512->256, relu (float4 dot)
  {
    const float4* __restrict__ glv = reinterpret_cast<const float4*>(gl);
    const float4* __restrict__ w1v = reinterpret_cast<const float4*>(fw1 + t * 512);
    float acc = fb1[t];
#pragma unroll 8
    for (int k = 0; k < 128; k++){
      float4 g = glv[k], w = w1v[k];
      acc += g.x * w.x + g.y * w.y + g.z * w.z + g.w * w.w;
    }
    hl[t] = fmaxf(acc, 0.f);
  }
  __syncthreads();
  // layer2: 256->3
  if (t < 3){
    const float4* __restrict__ hv  = reinterpret_cast<const float4*>(hl);
    const float4* __restrict__ w2v = reinterpret_cast<const float4*>(fw2 + t * 256);
    float r = fb2[t];
#pragma unroll 8
    for (int k = 0; k < 64; k++){
      float4 h = hv[k], w = w2v[k];
      r += h.x * w.x + h.y * w.y + h.z * w.z + h.w * w.w;
    }
    rawl[t] = r;
  }
  __syncthreads();
  if (t == 0){
    float cum = 0.f;
    for (int o = 0; o < 3; o++){
      float rv = rawl[o];
      out[O_RAW + b * 3 + o] = rv;
      cum += softplusf(rv) * 150.f + 5.f;  // SCALE=150
      out[O_BND + b * 3 + o] = cum;
      bnd[o] = cum;
    }
  }
  __syncthreads();

  // count regressor: LN(256) -> 256 relu -> 1 softplus
  float sc  = bsum256(fa, red);
  float sc2 = bsum256(fa * fa, red);
  float m2 = sc * (1.f / 256.f);
  float v2 = sc2 * (1.f / 256.f) - m2 * m2;
  float inv2 = rsqrtf(v2 + 1e-5f);
  hl[t] = (fa - m2) * inv2 * crg[t] + crb[t];
  __syncthreads();
  float h2;
  {
    const float4* __restrict__ hv  = reinterpret_cast<const float4*>(hl);
    const float4* __restrict__ w1v = reinterpret_cast<const float4*>(cw1 + t * 256);
    float acc2 = cb1[t];
#pragma unroll 8
    for (int k = 0; k < 64; k++){
      float4 h = hv[k], w = w1v[k];
      acc2 += h.x * w.x + h.y * w.y + h.z * w.z + h.w * w.w;
    }
    h2 = fmaxf(acc2, 0.f);
  }
  float pv = bsum256(h2 * cw2[t], red);
  if (t == 0){
    float pred = softplusf(pv + cb2[0]);
    out[O_CNT + b] = pred;
    int lvl = (pred > bnd[0]) + (pred > bnd[1]) + (pred > bnd[2]);
    const float QL[4] = {300.f, 500.f, 900.f, 1500.f};
    out[O_NQ + b] = QL[lvl];
  }

  // channel attention: gap -> 16 relu -> 256 sigmoid
  float gp = ws[WS_GAP + b * CC + t];
  __syncthreads();
  hl[t] = gp;
  __syncthreads();
  if (t < 16){
    const float4* __restrict__ hv  = reinterpret_cast<const float4*>(hl);
    const float4* __restrict__ w1v = reinterpret_cast<const float4*>(caw1 + t * 256);
    float a = cab1[t];
#pragma unroll 8
    for (int k = 0; k < 64; k++){
      float4 h = hv[k], w = w1v[k];
      a += h.x * w.x + h.y * w.y + h.z * w.z + h.w * w.w;
    }
    al[t] = fmaxf(a, 0.f);
  }
  __syncthreads();
  float a2 = cab2[t];
  {
    const float4* __restrict__ av  = reinterpret_cast<const float4*>(al);
    const float4* __restrict__ w2v = reinterpret_cast<const float4*>(caw2 + t * 16);
#pragma unroll
    for (int k = 0; k < 4; k++){
      float4 h = av[k], w = w2v[k];
      a2 += h.x * w.x + h.y * w.y + h.z * w.z + h.w * w.w;
    }
  }
  float cav = sigmoidf(a2);
  ws[WS_CA + b * CC + t]   = cav;
  ws[WS_CASW + b * CC + t] = cav * sw_w[t];
}

// ---------------- kernel 3: second ef pass — channel-split per-pixel reductions ----------------
// Block = 4 waves x 64 quads; wave w covers channels [64w,64w+64) with an 8-deep
// ping-pong register pipeline; LDS combine of the 4 per-wave partials.
__device__ __forceinline__ void px_acc(const float4& v, float ca, float cs,
                                       float4& sum, float4& mx, float4& sw){
  float a = clip5(v.x), b = clip5(v.y), c = clip5(v.z), d = clip5(v.w);
  sum.x += a * ca; sum.y += b * ca; sum.z += c * ca; sum.w += d * ca;
  mx.x = fmaxf(mx.x, a * ca); mx.y = fmaxf(mx.y, b * ca);
  mx.z = fmaxf(mx.z, c * ca); mx.w = fmaxf(mx.w, d * ca);
  sw.x = fmaf(a, cs, sw.x); sw.y = fmaf(b, cs, sw.y);
  sw.z = fmaf(c, cs, sw.z); sw.w = fmaf(d, cs, sw.w);
}

__global__ __launch_bounds__(256) void k_pixel(const float* __restrict__ ef,
                                               float* __restrict__ ws){
  int b = blockIdx.y;
  int t = threadIdx.x;
  int w = t >> 6, lane = t & 63;
  __shared__ float caL[256], cswL[256];
  __shared__ float4 part[3][4][QB];    // 12.3 KB
  caL[t]  = ws[WS_CA + b * CC + t];
  cswL[t] = ws[WS_CASW + b * CC + t];
  __syncthreads();

  int q = blockIdx.x * QB + lane;      // quad index
  const size_t st = HW / 4;            // 2500
  size_t off = (q < (int)st) ? (size_t)q : 0;   // clamp inactive lanes (safe reads)
  const float4* __restrict__ base =
      reinterpret_cast<const float4*>(ef + (size_t)b * CC * HW) + off;
  int c0 = w * 64;

  float4 sum = {0.f, 0.f, 0.f, 0.f};
  float4 mx  = {-1e30f, -1e30f, -1e30f, -1e30f};
  float4 sw  = {0.f, 0.f, 0.f, 0.f};

  float4 A[8], Bv[8];
#pragma unroll
  for (int j = 0; j < 8; j++) A[j] = base[(size_t)(c0 + j) * st];        // chunk 0
#pragma unroll
  for (int s = 0; s < 4; s++){
    int cA = c0 + (2 * s) * 8;
    int cB = c0 + (2 * s + 1) * 8;
#pragma unroll
    for (int j = 0; j < 8; j++) Bv[j] = base[(size_t)(cB + j) * st];     // load odd chunk
#pragma unroll
    for (int j = 0; j < 8; j++) px_acc(A[j], caL[cA + j], cswL[cA + j], sum, mx, sw);
    if (s < 3){
      int cN = c0 + (2 * s + 2) * 8;
#pragma unroll
      for (int j = 0; j < 8; j++) A[j] = base[(size_t)(cN + j) * st];    // load next even
    }
#pragma unroll
    for (int j = 0; j < 8; j++) px_acc(Bv[j], caL[cB + j], cswL[cB + j], sum, mx, sw);
  }

  part[0][w][lane] = sum;
  part[1][w][lane] = mx;
  part[2][w][lane] = sw;
  __syncthreads();
  if (t < QB){
    float4 S = part[0][0][t], M = part[1][0][t], W4 = part[2][0][t];
#pragma unroll
    for (int wv = 1; wv < 4; wv++){
      float4 s1 = part[0][wv][t], m1 = part[1][wv][t], w1 = part[2][wv][t];
      S.x += s1.x; S.y += s1.y; S.z += s1.z; S.w += s1.w;
      M.x = fmaxf(M.x, m1.x); M.y = fmaxf(M.y, m1.y);
      M.z = fmaxf(M.z, m1.z); M.w = fmaxf(M.w, m1.w);
      W4.x += w1.x; W4.y += w1.y; W4.z += w1.z; W4.w += w1.w;
    }
    int q2 = blockIdx.x * QB + t;
    if (q2 < (int)st){
      float4 avg = {S.x * (1.f / 256.f), S.y * (1.f / 256.f),
                    S.z * (1.f / 256.f), S.w * (1.f / 256.f)};
      reinterpret_cast<float4*>(ws + WS_SAVG + (size_t)b * HW)[q2] = avg;
      reinterpret_cast<float4*>(ws + WS_SMAX + (size_t)b * HW)[q2] = M;
      reinterpret_cast<float4*>(ws + WS_SW   + (size_t)b * HW)[q2] = W4;
    }
  }
}

// ---------------- kernel 4: 7x7 spatial-attn conv + wmap ----------------
__global__ __launch_bounds__(256) void k_conv(const float* __restrict__ ws,
                                              const float* __restrict__ sa_w,
                                              const float* __restrict__ sw_b,
                                              float* __restrict__ out){
  __shared__ float wc[98];
  if (threadIdx.x < 98) wc[threadIdx.x] = sa_w[threadIdx.x];
  __syncthreads();
  int b = blockIdx.y;
  int p = blockIdx.x * 256 + threadIdx.x;
  if (p >= HW) return;
  int h = p / WW, w = p - h * WW;
  const float* s0 = ws + WS_SAVG + (size_t)b * HW;
  const float* s1 = ws + WS_SMAX + (size_t)b * HW;
  float acc = 0.f;
#pragma unroll
  for (int kh = 0; kh < 7; kh++){
    int hy = h + kh - 3;
    if (hy < 0 || hy >= HH) continue;
#pragma unroll
    for (int kw = 0; kw < 7; kw++){
      int wx = w + kw - 3;
      if (wx < 0 || wx >= WW) continue;
      int q = hy * WW + wx;
      acc += s0[q] * wc[kh * 7 + kw] + s1[q] * wc[49 + kh * 7 + kw];
    }
  }
  float wm = sigmoidf(ws[WS_SW + (size_t)b * HW + p] * sigmoidf(acc) + sw_b[0]);
  out[O_WMAP + (size_t)b * HW + p] = wm;
}

// ---------------- kernel 5: per-batch threshold find (4-way search) + compact + ties ----------
// All wmap values are positive floats -> uint bit-pattern compare == float compare.
// Register tile rv[j] holds global index j*1024 + t, so chunked scans need no LDS mirror.
__global__ __launch_bounds__(1024) void k_select(const float* __restrict__ outw,
                                                 float* __restrict__ ws,
                                                 float* __restrict__ out){
  __shared__ unsigned long long red64[16];
  __shared__ unsigned red32[16];
  __shared__ unsigned slo, shi, sbc;
  __shared__ unsigned acnt, runbase;
  int b = blockIdx.x, t = threadIdx.x;
  int w = t >> 6, lane = t & 63;

  const float* src = outw + O_WMAP + (size_t)b * HW;
  unsigned rv[10];
#pragma unroll
  for (int j = 0; j < 10; j++){
    int i = t + j * 1024;
    rv[j] = (i < HW) ? __float_as_uint(src[i]) : 0u;  // 0 sentinel never counted (> u fails)
  }

  // find vthr = min u such that count(v > u) < KTOP, resolving 2 bits/round via 3 quartile
  // probes whose block counts are packed into one u64 (16-bit fields; total <= 10000).
  unsigned lo = 0u, hi = 0xFFFFFFFFu;
  while (lo < hi){
    unsigned span = hi - lo;
    unsigned q1 = lo + (span >> 2);
    unsigned q2 = lo + (span >> 1);
    unsigned q3 = lo + span - (span >> 2);
    unsigned long long pk = 0;
#pragma unroll
    for (int j = 0; j < 10; j++){
      unsigned v = rv[j];
      pk += (unsigned long long)(v > q1)
          + ((unsigned long long)(v > q2) << 16)
          + ((unsigned long long)(v > q3) << 32);
    }
#pragma unroll
    for (int o = 32; o; o >>= 1) pk += __shfl_down(pk, o, 64);
    if (lane == 0) red64[w] = pk;
    __syncthreads();
    if (t == 0){
      unsigned long long tot = 0;
#pragma unroll
      for (int q = 0; q < 16; q++) tot += red64[q];
      unsigned c1 = (unsigned)(tot & 0xFFFFu);
      unsigned c2 = (unsigned)((tot >> 16) & 0xFFFFu);
      unsigned c3 = (unsigned)((tot >> 32) & 0xFFFFu);
      unsigned nlo, nhi;
      if (c1 < (unsigned)KTOP)      { nlo = lo;      nhi = q1; }
      else if (c2 < (unsigned)KTOP) { nlo = q1 + 1u; nhi = q2; }
      else if (c3 < (unsigned)KTOP) { nlo = q2 + 1u; nhi = q3; }
      else                          { nlo = q3 + 1u; nhi = hi; }
      slo = nlo; shi = nhi;
    }
    __syncthreads();
    lo = slo; hi = shi;
    __syncthreads();
  }
  unsigned vthr = lo;

  // count strictly greater (nabove)
  {
    unsigned c = 0;
#pragma unroll
    for (int j = 0; j < 10; j++) c += (rv[j] > vthr) ? 1u : 0u;
#pragma unroll
    for (int o = 32; o; o >>= 1) c += __shfl_down((int)c, o, 64);
    if (lane == 0) red32[w] = c;
    __syncthreads();
    if (t == 0){
      unsigned tot = 0;
#pragma unroll
      for (int q = 0; q < 16; q++) tot += red32[q];
      sbc = tot;
      acnt = 0; runbase = 0;
    }
    __syncthreads();
  }
  unsigned nabove = sbc;                 // < KTOP by construction
  int neq = KTOP - (int)nabove;          // >= 1; #(v==vthr) >= neq guaranteed
  if (t == 0) reinterpret_cast<int*>(ws)[WS_SEL + b] = (int)nabove;

  // compact strictly-greater candidates to ws (wave-aggregated atomics; order-agnostic)
  unsigned long long* AK = reinterpret_cast<unsigned long long*>(ws + WS_AK) + (size_t)b * KTOP;
#pragma unroll
  for (int j = 0; j < 10; j++){
    int i = t + j * 1024;
    bool p = (i < HW) && (rv[j] > vthr);
    unsigned long long m = __ballot(p);
    unsigned base = 0;
    if (lane == 0 && m) base = atomicAdd(&acnt, (unsigned)__popcll(m));
    base = (unsigned)__shfl((int)base, 0, 64);
    if (p){
      unsigned pos = base + (unsigned)__popcll(m & ((1ull << lane) - 1ull));
      AK[pos] = ((unsigned long long)rv[j] << 32) | (unsigned long long)(0xFFFFFFFFu - (unsigned)i);
    }
  }

  // ties (== vthr): first `neq` by ascending index, ordered block scan with early exit
  for (int j = 0; j < 10; j++){
    int i = j * 1024 + t;
    bool eq = (i < HW) && (rv[j] == vthr);
    unsigned long long bal = __ballot(eq);
    if (lane == 0) red32[w] = (unsigned)__popcll(bal);
    __syncthreads();
    unsigned pre = runbase;
    for (int q = 0; q < w; q++) pre += red32[q];
    unsigned myr = pre + (unsigned)__popcll(bal & ((1ull << lane) - 1ull));
    if (eq && myr < (unsigned)neq){
      int pos = (int)nabove + (int)myr;
      float y = ((float)(i / WW) + 0.5f) * (1.f / HH);
      float x = ((float)(i % WW) + 0.5f) * (1.f / WW);
      float* rp = out + O_REF + ((size_t)b * KTOP + pos) * 4;
      rp[0] = x; rp[1] = y; rp[2] = 0.05f; rp[3] = 0.05f;
    }
    __syncthreads();
    if (t == 0){
      unsigned tot = 0;
#pragma unroll
      for (int q = 0; q < 16; q++) tot += red32[q];
      runbase += tot;
    }
    __syncthreads();
    if (runbase >= (unsigned)neq) break;   // uniform
  }
}

// ---------------- kernel 6: exact rank of strictly-greater candidates (96 blocks) -----------
__global__ __launch_bounds__(128) void k_rank(const float* __restrict__ ws,
                                              float* __restrict__ out){
  int b = blockIdx.x, chunk = blockIdx.y, t = threadIdx.x;
  int nA = reinterpret_cast<const int*>(ws)[WS_SEL + b];
  __shared__ unsigned long long K[KTOP];
  const unsigned long long* AK =
      reinterpret_cast<const unsigned long long*>(ws + WS_AK) + (size_t)b * KTOP;
  for (int i = t; i < nA; i += 128) K[i] = AK[i];
  __syncthreads();
  int i = chunk * 128 + t;
  if (i >= nA) return;
  unsigned long long Ki = K[i];
  int r = 0;
  for (int j = 0; j < nA; j++) r += (K[j] > Ki);
  unsigned idx = 0xFFFFFFFFu - (unsigned)(Ki & 0xFFFFFFFFull);
  float y = ((float)(idx / WW) + 0.5f) * (1.f / HH);
  float x = ((float)(idx % WW) + 0.5f) * (1.f / WW);
  float* rp = out + O_REF + ((size_t)b * KTOP + r) * 4;
  rp[0] = x; rp[1] = y; rp[2] = 0.05f; rp[3] = 0.05f;
}

extern "C" void kernel_launch(void* const* d_in, const int* in_sizes, int n_in,
                              void* d_out, int out_size, void* d_ws, size_t ws_size,
                              hipStream_t stream) {
  const float* df   = (const float*)d_in[0];
  const float* ef   = (const float*)d_in[1];
  const float* ln_g = (const float*)d_in[2];
  const float* ln_b = (const float*)d_in[3];
  const float* fw1  = (const float*)d_in[4];
  const float* fb1  = (const float*)d_in[5];
  const float* fw2  = (const float*)d_in[6];
  const float* fb2  = (const float*)d_in[7];
  const float* crg  = (const float*)d_in[8];
  const float* crb  = (const float*)d_in[9];
  const float* cw1  = (const float*)d_in[10];
  const float* cb1  = (const float*)d_in[11];
  const float* cw2  = (const float*)d_in[12];
  const float* cb2  = (const float*)d_in[13];
  const float* caw1 = (const float*)d_in[14];
  const float* cab1 = (const float*)d_in[15];
  const float* caw2 = (const float*)d_in[16];
  const float* cab2 = (const float*)d_in[17];
  const float* sa_w = (const float*)d_in[18];
  const float* sw_w = (const float*)d_in[19];
  const float* sw_b = (const float*)d_in[20];
  float* out = (float*)d_out;
  float* ws  = (float*)d_ws;

  k_reduce<<<4096, 256, 0, stream>>>(df, ef, ws);
  k_head<<<8, 256, 0, stream>>>(ws, ln_g, ln_b, fw1, fb1, fw2, fb2,
                                crg, crb, cw1, cb1, cw2, cb2,
                                caw1, cab1, caw2, cab2, sw_w, out);
  k_pixel<<<dim3(40, 8), 256, 0, stream>>>(ef, ws);
  k_conv<<<dim3(40, 8), 256, 0, stream>>>(ws, sa_w, sw_b, out);
  k_select<<<8, 1024, 0, stream>>>(out, ws, out);
  k_rank<<<dim3(8, 12), 128, 0, stream>>>(ws, out);
}